// Round 1
// baseline (499.289 us; speedup 1.0000x reference)
//
#include <hip/hip_runtime.h>
#include <hip/hip_bf16.h>

#define N_NODES 50000
#define N_EDGES 800000
#define MP 50048  // N_NODES padded up to multiple of 64 (GEMM row tiles)

typedef unsigned short ushort_t;
typedef unsigned int uint_t;
typedef __attribute__((ext_vector_type(8))) __bf16 bf16x8;
typedef __attribute__((ext_vector_type(4))) float f32x4;

__device__ __forceinline__ float bf2f(ushort_t u) {
    union { uint_t i; float f; } v; v.i = ((uint_t)u) << 16; return v.f;
}
__device__ __forceinline__ ushort_t f2bf(float f) {
    union { float f; uint_t i; } v; v.f = f;
    uint_t u = v.i;
    return (ushort_t)((u + 0x7FFFu + ((u >> 16) & 1u)) >> 16);
}

// ---------------- CSR build ----------------
__global__ void deg_k(const int* __restrict__ dst, int* __restrict__ deg, int E) {
    int e = blockIdx.x * 256 + threadIdx.x;
    if (e < E) atomicAdd(&deg[dst[e]], 1);
}

__global__ void scan1_k(const int* __restrict__ deg, int* __restrict__ offs,
                        int* __restrict__ bsum, int n) {
    __shared__ int s[256];
    int i = blockIdx.x * 256 + threadIdx.x;
    int v = (i < n) ? deg[i] : 0;
    s[threadIdx.x] = v;
    __syncthreads();
    #pragma unroll
    for (int d = 1; d < 256; d <<= 1) {
        int t = (threadIdx.x >= d) ? s[threadIdx.x - d] : 0;
        __syncthreads();
        s[threadIdx.x] += t;
        __syncthreads();
    }
    if (i < n) offs[i] = s[threadIdx.x] - v;   // exclusive
    if (threadIdx.x == 255) bsum[blockIdx.x] = s[255];
}

__global__ void scan2_k(int* __restrict__ bsum, int nb) {  // single block
    __shared__ int s[256];
    int v = (threadIdx.x < nb) ? bsum[threadIdx.x] : 0;
    s[threadIdx.x] = v;
    __syncthreads();
    #pragma unroll
    for (int d = 1; d < 256; d <<= 1) {
        int t = (threadIdx.x >= d) ? s[threadIdx.x - d] : 0;
        __syncthreads();
        s[threadIdx.x] += t;
        __syncthreads();
    }
    if (threadIdx.x < nb) bsum[threadIdx.x] = s[threadIdx.x] - v;  // exclusive
}

__global__ void scan3_k(int* __restrict__ offs, const int* __restrict__ bsum, int n, int E) {
    int i = blockIdx.x * 256 + threadIdx.x;
    if (i < n) offs[i] += bsum[blockIdx.x];
    if (i == 0) offs[n] = E;
}

__global__ void scat_k(const int* __restrict__ src, const int* __restrict__ dst,
                       int* __restrict__ cur, int* __restrict__ csrc, int E) {
    int e = blockIdx.x * 256 + threadIdx.x;
    if (e < E) {
        int p = atomicAdd(&cur[dst[e]], 1);
        csrc[p] = src[e];
    }
}

// ---------------- f32 -> bf16 convert ----------------
__global__ void cvt_k(const float* __restrict__ x, ushort_t* __restrict__ o, long long n) {
    long long i = ((long long)blockIdx.x * 256 + threadIdx.x) * 4;
    if (i >= n) return;
    float4 v = *reinterpret_cast<const float4*>(x + i);
    uint2 w;
    w.x = (uint_t)f2bf(v.x) | ((uint_t)f2bf(v.y) << 16);
    w.y = (uint_t)f2bf(v.z) | ((uint_t)f2bf(v.w) << 16);
    *reinterpret_cast<uint2*>(o + i) = w;
}

// ---------------- weight packing into MFMA B-fragment order ----------------
// frag (kt, ct): value(lane, j) = W[kt*32 + (lane>>4)*8 + j][ct*16 + (lane&15)]
__global__ void pack_k(const float* __restrict__ W, ushort_t* __restrict__ P, int K, int NOUT) {
    int tid = blockIdx.x * 256 + threadIdx.x;
    int total = (K / 32) * (NOUT / 16) * 64;
    if (tid >= total) return;
    int lane = tid & 63;
    int frag = tid >> 6;
    int nct = NOUT / 16;
    int ct = frag % nct;
    int kt = frag / nct;
    int col = ct * 16 + (lane & 15);
    int k0 = kt * 32 + (lane >> 4) * 8;
    uint_t w[4];
    #pragma unroll
    for (int p = 0; p < 4; ++p) {
        ushort_t lo = f2bf(W[(long long)(k0 + 2 * p) * NOUT + col]);
        ushort_t hi = f2bf(W[(long long)(k0 + 2 * p + 1) * NOUT + col]);
        w[p] = (uint_t)lo | ((uint_t)hi << 16);
    }
    uint4* dst = reinterpret_cast<uint4*>(P) + tid;
    *dst = make_uint4(w[0], w[1], w[2], w[3]);
}

// ---------------- mean aggregation over CSR (one wave per node) ----------------
template <int F>
__global__ void agg_mean_k(const ushort_t* __restrict__ X, const int* __restrict__ offs,
                           const int* __restrict__ csrc, ushort_t* __restrict__ M, int n) {
    int wid = (blockIdx.x * 256 + threadIdx.x) >> 6;
    if (wid >= n) return;
    int lane = threadIdx.x & 63;
    constexpr int V = F / 64;  // 4 (F=256) or 2 (F=128)
    int beg = offs[wid], end = offs[wid + 1];
    float acc[V];
    #pragma unroll
    for (int i = 0; i < V; ++i) acc[i] = 0.f;
    int col = lane * V;
    for (int e = beg; e < end; ++e) {
        int s = csrc[e];
        const ushort_t* row = X + (long long)s * F + col;
        if (V == 4) {
            uint2 d = *reinterpret_cast<const uint2*>(row);
            acc[0] += bf2f(d.x & 0xffff);
            acc[1] += bf2f(d.x >> 16);
            acc[2] += bf2f(d.y & 0xffff);
            acc[3] += bf2f(d.y >> 16);
        } else {
            uint_t d = *reinterpret_cast<const uint_t*>(row);
            acc[0] += bf2f(d & 0xffff);
            acc[1] += bf2f(d >> 16);
        }
    }
    float inv = 1.f / fmaxf((float)(end - beg), 1.f);
    if (V == 4) {
        uint2 w;
        w.x = (uint_t)f2bf(acc[0] * inv) | ((uint_t)f2bf(acc[1] * inv) << 16);
        w.y = (uint_t)f2bf(acc[2] * inv) | ((uint_t)f2bf(acc[3] * inv) << 16);
        *reinterpret_cast<uint2*>(M + (long long)wid * F + col) = w;
    } else {
        uint_t w = (uint_t)f2bf(acc[0] * inv) | ((uint_t)f2bf(acc[1] * inv) << 16);
        *reinterpret_cast<uint_t*>(M + (long long)wid * F + col) = w;
    }
}

// ---------------- fused SAGE GEMM: out = Am@Bl + Ax@Br + bias ----------------
// A row-major bf16 [MP][K]; B packed frag-order bf16.
// MFMA 16x16x32 bf16. A frag: row=lane&15, k=(lane>>4)*8+j. B frag: col=lane&15, k=(lane>>4)*8+j.
// C frag: col=lane&15, row=(lane>>4)*4+reg.
template <int K, int NOUT, bool RELU, bool F32OUT>
__global__ __launch_bounds__(256) void sage_gemm_k(
    const ushort_t* __restrict__ Am, const ushort_t* __restrict__ Ax,
    const ushort_t* __restrict__ Bl, const ushort_t* __restrict__ Br,
    const float* __restrict__ bias, ushort_t* __restrict__ outb,
    float* __restrict__ outf, int M) {
    constexpr int CT = NOUT / 16;
    constexpr int KT = K / 32;
    int wave = threadIdx.x >> 6;
    int lane = threadIdx.x & 63;
    int rowBase = blockIdx.x * 64 + wave * 16;

    f32x4 acc[CT];
    #pragma unroll
    for (int i = 0; i < CT; ++i) acc[i] = (f32x4){0.f, 0.f, 0.f, 0.f};

    int arow = rowBase + (lane & 15);
    int kgrp = (lane >> 4) * 8;

    #pragma unroll
    for (int kk = 0; kk < 2 * KT; ++kk) {
        const ushort_t* A = (kk < KT) ? Am : Ax;
        const ushort_t* B = (kk < KT) ? Bl : Br;
        int kt = kk & (KT - 1);
        bf16x8 a = *reinterpret_cast<const bf16x8*>(A + (long long)arow * K + kt * 32 + kgrp);
        #pragma unroll
        for (int ct = 0; ct < CT; ++ct) {
            bf16x8 b = *reinterpret_cast<const bf16x8*>(B + ((long long)(kt * CT + ct) * 64 + lane) * 8);
            acc[ct] = __builtin_amdgcn_mfma_f32_16x16x32_bf16(a, b, acc[ct], 0, 0, 0);
        }
    }

    int colb = lane & 15;
    int r0 = (lane >> 4) * 4;
    #pragma unroll
    for (int ct = 0; ct < CT; ++ct) {
        int col = ct * 16 + colb;
        float bv = bias[col];
        #pragma unroll
        for (int r = 0; r < 4; ++r) {
            int row = rowBase + r0 + r;
            if (row < M) {
                float v = acc[ct][r] + bv;
                if (RELU) v = fmaxf(v, 0.f);
                if (F32OUT) outf[(long long)row * NOUT + col] = v;
                else outb[(long long)row * NOUT + col] = f2bf(v);
            }
        }
    }
}

// ---------------- log_softmax over rows of 64 (one wave per row) ----------------
__global__ void lsm_k(const float* __restrict__ h, float* __restrict__ o, int M) {
    int wid = (blockIdx.x * 256 + threadIdx.x) >> 6;
    if (wid >= M) return;
    int lane = threadIdx.x & 63;
    float v = h[(long long)wid * 64 + lane];
    float m = v;
    #pragma unroll
    for (int d = 32; d >= 1; d >>= 1) m = fmaxf(m, __shfl_xor(m, d));
    float e = expf(v - m);
    float s = e;
    #pragma unroll
    for (int d = 32; d >= 1; d >>= 1) s += __shfl_xor(s, d);
    o[(long long)wid * 64 + lane] = v - m - logf(s);
}

extern "C" void kernel_launch(void* const* d_in, const int* in_sizes, int n_in,
                              void* d_out, int out_size, void* d_ws, size_t ws_size,
                              hipStream_t stream) {
    const float* x   = (const float*)d_in[0];
    const int*   ei  = (const int*)d_in[1];
    const float* W1l = (const float*)d_in[2];
    const float* b1  = (const float*)d_in[3];
    const float* W1r = (const float*)d_in[4];
    const float* W2l = (const float*)d_in[5];
    const float* b2  = (const float*)d_in[6];
    const float* W2r = (const float*)d_in[7];
    const float* W3l = (const float*)d_in[8];
    const float* b3  = (const float*)d_in[9];
    const float* W3r = (const float*)d_in[10];
    const int* esrc = ei;
    const int* edst = ei + N_EDGES;

    char* ws = (char*)d_ws;
    size_t off = 0;
    auto alloc = [&](size_t b) { void* p = ws + off; off = (off + b + 255) & ~(size_t)255; return p; };
    ushort_t* Xbf  = (ushort_t*)alloc((size_t)MP * 256 * 2);
    ushort_t* H1   = (ushort_t*)alloc((size_t)MP * 256 * 2);
    ushort_t* H2   = (ushort_t*)alloc((size_t)MP * 128 * 2);
    ushort_t* Mb   = (ushort_t*)alloc((size_t)MP * 256 * 2);
    int* offs = (int*)alloc((N_NODES + 1) * 4);
    int* cur  = (int*)alloc(N_NODES * 4);
    int* csrc = (int*)alloc(N_EDGES * 4);
    int* bsum = (int*)alloc(256 * 4);
    ushort_t* pW1l = (ushort_t*)alloc(256 * 256 * 2);
    ushort_t* pW1r = (ushort_t*)alloc(256 * 256 * 2);
    ushort_t* pW2l = (ushort_t*)alloc(256 * 128 * 2);
    ushort_t* pW2r = (ushort_t*)alloc(256 * 128 * 2);
    ushort_t* pW3l = (ushort_t*)alloc(128 * 64 * 2);
    ushort_t* pW3r = (ushort_t*)alloc(128 * 64 * 2);

    int nScanBlocks = (N_NODES + 255) / 256;  // 196

    // CSR build (reused by all 3 layers)
    hipMemsetAsync(cur, 0, N_NODES * 4, stream);
    deg_k<<<(N_EDGES + 255) / 256, 256, 0, stream>>>(edst, cur, N_EDGES);
    scan1_k<<<nScanBlocks, 256, 0, stream>>>(cur, offs, bsum, N_NODES);
    scan2_k<<<1, 256, 0, stream>>>(bsum, nScanBlocks);
    scan3_k<<<nScanBlocks, 256, 0, stream>>>(offs, bsum, N_NODES, N_EDGES);
    hipMemcpyAsync(cur, offs, N_NODES * 4, hipMemcpyDeviceToDevice, stream);
    scat_k<<<(N_EDGES + 255) / 256, 256, 0, stream>>>(esrc, edst, cur, csrc, N_EDGES);

    // x -> bf16
    cvt_k<<<(int)(((long long)N_NODES * 256 / 4 + 255) / 256), 256, 0, stream>>>(
        x, Xbf, (long long)N_NODES * 256);

    // pack weights into fragment order
    pack_k<<<(8 * 16 * 64 + 255) / 256, 256, 0, stream>>>(W1l, pW1l, 256, 256);
    pack_k<<<(8 * 16 * 64 + 255) / 256, 256, 0, stream>>>(W1r, pW1r, 256, 256);
    pack_k<<<(8 * 8 * 64 + 255) / 256, 256, 0, stream>>>(W2l, pW2l, 256, 128);
    pack_k<<<(8 * 8 * 64 + 255) / 256, 256, 0, stream>>>(W2r, pW2r, 256, 128);
    pack_k<<<(4 * 4 * 64 + 255) / 256, 256, 0, stream>>>(W3l, pW3l, 128, 64);
    pack_k<<<(4 * 4 * 64 + 255) / 256, 256, 0, stream>>>(W3r, pW3r, 128, 64);

    int aggGrid = (N_NODES * 64 + 255) / 256;   // 12500
    int gemmGrid = (N_NODES + 63) / 64;         // 782

    // layer 1: h1 = relu(mean@W1l + b1 + x@W1r)   [N,256]
    agg_mean_k<256><<<aggGrid, 256, 0, stream>>>(Xbf, offs, csrc, Mb, N_NODES);
    sage_gemm_k<256, 256, true, false><<<gemmGrid, 256, 0, stream>>>(
        Mb, Xbf, pW1l, pW1r, b1, H1, nullptr, N_NODES);

    // layer 2: h2 = relu(mean@W2l + b2 + h1@W2r)  [N,128]
    agg_mean_k<256><<<aggGrid, 256, 0, stream>>>(H1, offs, csrc, Mb, N_NODES);
    sage_gemm_k<256, 128, true, false><<<gemmGrid, 256, 0, stream>>>(
        Mb, H1, pW2l, pW2r, b2, H2, nullptr, N_NODES);

    // layer 3: h3 = mean@W3l + b3 + h2@W3r        [N,64] -> d_out f32
    agg_mean_k<128><<<aggGrid, 256, 0, stream>>>(H2, offs, csrc, Mb, N_NODES);
    float* hout = (float*)d_out;
    sage_gemm_k<128, 64, false, true><<<gemmGrid, 256, 0, stream>>>(
        Mb, H2, pW3l, pW3r, b3, nullptr, hout, N_NODES);

    // log_softmax -> second half of d_out
    lsm_k<<<aggGrid, 256, 0, stream>>>(hout, hout + (long long)N_NODES * 64, N_NODES);
}

// Round 2
// 319.312 us; speedup vs baseline: 1.5636x; 1.5636x over previous
//
#include <hip/hip_runtime.h>
#include <hip/hip_bf16.h>

#define N_NODES 50000
#define N_EDGES 800000
#define MP 50048  // N_NODES padded to multiple of 64

typedef unsigned short ushort_t;
typedef unsigned int uint_t;
typedef __attribute__((ext_vector_type(8))) __bf16 bf16x8;
typedef __attribute__((ext_vector_type(4))) float f32x4;

__device__ __forceinline__ float bf2f(uint_t u) {
    union { uint_t i; float f; } v; v.i = u << 16; return v.f;
}
__device__ __forceinline__ ushort_t f2bf(float f) {
    union { float f; uint_t i; } v; v.f = f;
    uint_t u = v.i;
    return (ushort_t)((u + 0x7FFFu + ((u >> 16) & 1u)) >> 16);
}
__device__ __forceinline__ void acc8(float* acc, uint4 d) {
    acc[0] += bf2f(d.x & 0xffff); acc[1] += bf2f(d.x >> 16);
    acc[2] += bf2f(d.y & 0xffff); acc[3] += bf2f(d.y >> 16);
    acc[4] += bf2f(d.z & 0xffff); acc[5] += bf2f(d.z >> 16);
    acc[6] += bf2f(d.w & 0xffff); acc[7] += bf2f(d.w >> 16);
}

// ---------------- CSR build ----------------
__global__ void deg_k(const int* __restrict__ dst, int* __restrict__ deg, int E) {
    int e = blockIdx.x * 256 + threadIdx.x;
    if (e < E) atomicAdd(&deg[dst[e]], 1);
}

__global__ void scan1_k(const int* __restrict__ deg, int* __restrict__ offs,
                        int* __restrict__ bsum, int n) {
    __shared__ int s[256];
    int i = blockIdx.x * 256 + threadIdx.x;
    int v = (i < n) ? deg[i] : 0;
    s[threadIdx.x] = v;
    __syncthreads();
    #pragma unroll
    for (int d = 1; d < 256; d <<= 1) {
        int t = (threadIdx.x >= d) ? s[threadIdx.x - d] : 0;
        __syncthreads();
        s[threadIdx.x] += t;
        __syncthreads();
    }
    if (i < n) offs[i] = s[threadIdx.x] - v;   // exclusive
    if (threadIdx.x == 255) bsum[blockIdx.x] = s[255];
}

__global__ void scan2_k(int* __restrict__ bsum, int nb) {  // single block
    __shared__ int s[256];
    int v = (threadIdx.x < nb) ? bsum[threadIdx.x] : 0;
    s[threadIdx.x] = v;
    __syncthreads();
    #pragma unroll
    for (int d = 1; d < 256; d <<= 1) {
        int t = (threadIdx.x >= d) ? s[threadIdx.x - d] : 0;
        __syncthreads();
        s[threadIdx.x] += t;
        __syncthreads();
    }
    if (threadIdx.x < nb) bsum[threadIdx.x] = s[threadIdx.x] - v;  // exclusive
}

__global__ void scan3_k(int* __restrict__ offs, const int* __restrict__ bsum, int n, int E) {
    int i = blockIdx.x * 256 + threadIdx.x;
    if (i < n) offs[i] += bsum[blockIdx.x];
    if (i == 0) offs[n] = E;
}

__global__ void scat_k(const int* __restrict__ src, const int* __restrict__ dst,
                       int* __restrict__ cur, int* __restrict__ csrc, int E) {
    int e = blockIdx.x * 256 + threadIdx.x;
    if (e < E) {
        int p = atomicAdd(&cur[dst[e]], 1);
        csrc[p] = src[e];
    }
}

// ---------------- f32 -> bf16 convert ----------------
__global__ void cvt_k(const float* __restrict__ x, ushort_t* __restrict__ o, long long n) {
    long long i = ((long long)blockIdx.x * 256 + threadIdx.x) * 4;
    if (i >= n) return;
    float4 v = *reinterpret_cast<const float4*>(x + i);
    uint2 w;
    w.x = (uint_t)f2bf(v.x) | ((uint_t)f2bf(v.y) << 16);
    w.y = (uint_t)f2bf(v.z) | ((uint_t)f2bf(v.w) << 16);
    *reinterpret_cast<uint2*>(o + i) = w;
}

// ---------------- weight-pair packing into MFMA B-fragment order ----------------
// packs [Wl | Wr] (each [K,F]) as one [K, 2F] matrix in frag order.
// frag (kt, ct): value(lane, j) = W[kt*32 + (lane>>4)*8 + j][ct*16 + (lane&15)]
__global__ void pack2_k(const float* __restrict__ Wl, const float* __restrict__ Wr,
                        ushort_t* __restrict__ P, int K, int F) {
    int NOUT = 2 * F;
    int tid = blockIdx.x * 256 + threadIdx.x;
    int total = (K / 32) * (NOUT / 16) * 64;
    if (tid >= total) return;
    int lane = tid & 63;
    int frag = tid >> 6;
    int nct = NOUT / 16;
    int ct = frag % nct;
    int kt = frag / nct;
    int col = ct * 16 + (lane & 15);
    const float* W = (col < F) ? Wl : Wr;
    int c = (col < F) ? col : col - F;
    int k0 = kt * 32 + (lane >> 4) * 8;
    uint_t w[4];
    #pragma unroll
    for (int p = 0; p < 4; ++p) {
        ushort_t lo = f2bf(W[(long long)(k0 + 2 * p) * F + c]);
        ushort_t hi = f2bf(W[(long long)(k0 + 2 * p + 1) * F + c]);
        w[p] = (uint_t)lo | ((uint_t)hi << 16);
    }
    *(reinterpret_cast<uint4*>(P) + tid) = make_uint4(w[0], w[1], w[2], w[3]);
}

// ---------------- GEMM: C[MP,NOUT] = A[MP,K] @ Bp (frag-packed) ----------------
// block = 4 waves, 64 rows; wave owns NOUT/4 cols (CTW col-tiles); 4 row-frags.
template <int K, int NOUT>
__global__ __launch_bounds__(256) void gemm_k(
    const ushort_t* __restrict__ A, const ushort_t* __restrict__ Bp,
    ushort_t* __restrict__ C) {
    constexpr int KT = K / 32;
    constexpr int CTW = NOUT / 64;
    int wave = threadIdx.x >> 6;
    int lane = threadIdx.x & 63;
    int rowBase = blockIdx.x * 64;
    int arowoff = lane & 15;
    int kgrp = (lane >> 4) * 8;
    int ct0 = wave * CTW;

    f32x4 acc[4][CTW];
    #pragma unroll
    for (int r = 0; r < 4; ++r)
        #pragma unroll
        for (int c = 0; c < CTW; ++c) acc[r][c] = (f32x4){0.f, 0.f, 0.f, 0.f};

    const ushort_t* Ab = A + (long long)rowBase * K + kgrp;
    #pragma unroll
    for (int kt = 0; kt < KT; ++kt) {
        bf16x8 a[4];
        #pragma unroll
        for (int r = 0; r < 4; ++r)
            a[r] = *reinterpret_cast<const bf16x8*>(
                Ab + (long long)(r * 16 + arowoff) * K + kt * 32);
        #pragma unroll
        for (int ct = 0; ct < CTW; ++ct) {
            bf16x8 b = *reinterpret_cast<const bf16x8*>(
                Bp + ((long long)(kt * (NOUT / 16) + ct0 + ct) * 64 + lane) * 8);
            #pragma unroll
            for (int r = 0; r < 4; ++r)
                acc[r][ct] = __builtin_amdgcn_mfma_f32_16x16x32_bf16(a[r], b, acc[r][ct], 0, 0, 0);
        }
    }

    int colb = lane & 15;
    int r0 = (lane >> 4) * 4;
    #pragma unroll
    for (int r = 0; r < 4; ++r) {
        #pragma unroll
        for (int ct = 0; ct < CTW; ++ct) {
            int col = (ct0 + ct) * 16 + colb;
            #pragma unroll
            for (int j = 0; j < 4; ++j) {
                int row = rowBase + r * 16 + r0 + j;
                C[(long long)row * NOUT + col] = f2bf(acc[r][ct][j]);
            }
        }
    }
}

// ---------------- fused aggregate + epilogue ----------------
// C = [P | R] rows of width 2F. out = act(segmean_gather(P) + R + bias).
// One wave per node; LPG lanes cover a row; 64/LPG edges in flight per iter, unroll 4.
// FINAL: F=64, write f32 h to hout and fused log_softmax to lout.
template <int F, bool RELU, bool FINAL>
__global__ __launch_bounds__(256) void agg_k(
    const ushort_t* __restrict__ C, const int* __restrict__ offs,
    const int* __restrict__ csrc, const float* __restrict__ bias,
    ushort_t* __restrict__ H, float* __restrict__ hout,
    float* __restrict__ lout, int n) {
    int node = (blockIdx.x * 256 + threadIdx.x) >> 6;
    if (node >= n) return;
    int lane = threadIdx.x & 63;
    constexpr int LPG = FINAL ? 32 : (F / 8);   // lanes per gather group
    constexpr int VC  = FINAL ? 2 : 8;          // cols per lane
    constexpr int G   = 64 / LPG;               // edges in flight
    int g = lane / LPG;
    int sub = lane % LPG;
    int colbase = sub * VC;
    const long long stride = 2 * F;
    int beg = offs[node], end = offs[node + 1];

    float acc[VC];
    #pragma unroll
    for (int i = 0; i < VC; ++i) acc[i] = 0.f;

    int e = beg + g;
    if constexpr (!FINAL) {
        while (e + 3 * G < end) {
            int s0 = csrc[e], s1 = csrc[e + G], s2 = csrc[e + 2 * G], s3 = csrc[e + 3 * G];
            uint4 d0 = *reinterpret_cast<const uint4*>(C + s0 * stride + colbase);
            uint4 d1 = *reinterpret_cast<const uint4*>(C + s1 * stride + colbase);
            uint4 d2 = *reinterpret_cast<const uint4*>(C + s2 * stride + colbase);
            uint4 d3 = *reinterpret_cast<const uint4*>(C + s3 * stride + colbase);
            acc8(acc, d0); acc8(acc, d1); acc8(acc, d2); acc8(acc, d3);
            e += 4 * G;
        }
        while (e < end) {
            int s = csrc[e];
            uint4 d = *reinterpret_cast<const uint4*>(C + s * stride + colbase);
            acc8(acc, d);
            e += G;
        }
    } else {
        while (e + 3 * G < end) {
            int s0 = csrc[e], s1 = csrc[e + G], s2 = csrc[e + 2 * G], s3 = csrc[e + 3 * G];
            uint_t d0 = *reinterpret_cast<const uint_t*>(C + s0 * stride + colbase);
            uint_t d1 = *reinterpret_cast<const uint_t*>(C + s1 * stride + colbase);
            uint_t d2 = *reinterpret_cast<const uint_t*>(C + s2 * stride + colbase);
            uint_t d3 = *reinterpret_cast<const uint_t*>(C + s3 * stride + colbase);
            acc[0] += bf2f(d0 & 0xffff) + bf2f(d1 & 0xffff) + bf2f(d2 & 0xffff) + bf2f(d3 & 0xffff);
            acc[1] += bf2f(d0 >> 16) + bf2f(d1 >> 16) + bf2f(d2 >> 16) + bf2f(d3 >> 16);
            e += 4 * G;
        }
        while (e < end) {
            int s = csrc[e];
            uint_t d = *reinterpret_cast<const uint_t*>(C + s * stride + colbase);
            acc[0] += bf2f(d & 0xffff);
            acc[1] += bf2f(d >> 16);
            e += G;
        }
    }

    // combine partial sums across groups (after this, ALL lanes hold totals)
    #pragma unroll
    for (int off = LPG; off < 64; off <<= 1) {
        #pragma unroll
        for (int i = 0; i < VC; ++i) acc[i] += __shfl_xor(acc[i], off);
    }

    float inv = 1.f / fmaxf((float)(end - beg), 1.f);

    if constexpr (!FINAL) {
        if (lane < LPG) {
            uint4 rr = *reinterpret_cast<const uint4*>(C + (long long)node * stride + F + colbase);
            float r[8];
            r[0] = bf2f(rr.x & 0xffff); r[1] = bf2f(rr.x >> 16);
            r[2] = bf2f(rr.y & 0xffff); r[3] = bf2f(rr.y >> 16);
            r[4] = bf2f(rr.z & 0xffff); r[5] = bf2f(rr.z >> 16);
            r[6] = bf2f(rr.w & 0xffff); r[7] = bf2f(rr.w >> 16);
            float4 bA = *reinterpret_cast<const float4*>(bias + colbase);
            float4 bB = *reinterpret_cast<const float4*>(bias + colbase + 4);
            float bv[8] = {bA.x, bA.y, bA.z, bA.w, bB.x, bB.y, bB.z, bB.w};
            uint_t w[4];
            #pragma unroll
            for (int p = 0; p < 4; ++p) {
                float v0 = acc[2 * p] * inv + r[2 * p] + bv[2 * p];
                float v1 = acc[2 * p + 1] * inv + r[2 * p + 1] + bv[2 * p + 1];
                if (RELU) { v0 = fmaxf(v0, 0.f); v1 = fmaxf(v1, 0.f); }
                w[p] = (uint_t)f2bf(v0) | ((uint_t)f2bf(v1) << 16);
            }
            *reinterpret_cast<uint4*>(H + (long long)node * F + colbase) =
                make_uint4(w[0], w[1], w[2], w[3]);
        }
    } else {
        uint_t rr = *reinterpret_cast<const uint_t*>(C + (long long)node * stride + F + colbase);
        float2 bv = *reinterpret_cast<const float2*>(bias + colbase);
        float v0 = acc[0] * inv + bf2f(rr & 0xffff) + bv.x;
        float v1 = acc[1] * inv + bf2f(rr >> 16) + bv.y;
        // fused log_softmax over the 64 cols (held 2-per-lane on each 32-lane half)
        float m = fmaxf(v0, v1);
        #pragma unroll
        for (int off = 16; off >= 1; off >>= 1) m = fmaxf(m, __shfl_xor(m, off));
        float s = expf(v0 - m) + expf(v1 - m);
        #pragma unroll
        for (int off = 16; off >= 1; off >>= 1) s += __shfl_xor(s, off);
        float ls = logf(s);
        if (lane < 32) {
            *reinterpret_cast<float2*>(hout + (long long)node * 64 + colbase) =
                make_float2(v0, v1);
            *reinterpret_cast<float2*>(lout + (long long)node * 64 + colbase) =
                make_float2(v0 - m - ls, v1 - m - ls);
        }
    }
}

extern "C" void kernel_launch(void* const* d_in, const int* in_sizes, int n_in,
                              void* d_out, int out_size, void* d_ws, size_t ws_size,
                              hipStream_t stream) {
    const float* x   = (const float*)d_in[0];
    const int*   ei  = (const int*)d_in[1];
    const float* W1l = (const float*)d_in[2];
    const float* b1  = (const float*)d_in[3];
    const float* W1r = (const float*)d_in[4];
    const float* W2l = (const float*)d_in[5];
    const float* b2  = (const float*)d_in[6];
    const float* W2r = (const float*)d_in[7];
    const float* W3l = (const float*)d_in[8];
    const float* b3  = (const float*)d_in[9];
    const float* W3r = (const float*)d_in[10];
    const int* esrc = ei;
    const int* edst = ei + N_EDGES;

    char* ws = (char*)d_ws;
    size_t off = 0;
    auto alloc = [&](size_t b) { void* p = ws + off; off = (off + b + 255) & ~(size_t)255; return p; };
    // bufA: Xbf, later C2.  bufB: C1, later H2.  bufC: H1, later C3.
    ushort_t* bufA = (ushort_t*)alloc((size_t)MP * 256 * 2);
    ushort_t* bufB = (ushort_t*)alloc((size_t)MP * 512 * 2);
    ushort_t* bufC = (ushort_t*)alloc((size_t)MP * 256 * 2);
    int* offs = (int*)alloc((N_NODES + 1) * 4);
    int* cur  = (int*)alloc(N_NODES * 4);
    int* csrc = (int*)alloc(N_EDGES * 4);
    int* bsum = (int*)alloc(256 * 4);
    ushort_t* pB1 = (ushort_t*)alloc(256 * 512 * 2);
    ushort_t* pB2 = (ushort_t*)alloc(256 * 256 * 2);
    ushort_t* pB3 = (ushort_t*)alloc(128 * 128 * 2);

    ushort_t* Xbf = bufA;
    ushort_t* C1  = bufB;
    ushort_t* H1  = bufC;
    ushort_t* C2  = bufA;
    ushort_t* H2  = bufB;
    ushort_t* C3  = bufC;

    int nScanBlocks = (N_NODES + 255) / 256;  // 196

    // CSR build (reused by all 3 layers)
    hipMemsetAsync(cur, 0, N_NODES * 4, stream);
    deg_k<<<(N_EDGES + 255) / 256, 256, 0, stream>>>(edst, cur, N_EDGES);
    scan1_k<<<nScanBlocks, 256, 0, stream>>>(cur, offs, bsum, N_NODES);
    scan2_k<<<1, 256, 0, stream>>>(bsum, nScanBlocks);
    scan3_k<<<nScanBlocks, 256, 0, stream>>>(offs, bsum, N_NODES, N_EDGES);
    hipMemcpyAsync(cur, offs, N_NODES * 4, hipMemcpyDeviceToDevice, stream);
    scat_k<<<(N_EDGES + 255) / 256, 256, 0, stream>>>(esrc, edst, cur, csrc, N_EDGES);

    // x -> bf16
    cvt_k<<<(int)(((long long)N_NODES * 256 / 4 + 255) / 256), 256, 0, stream>>>(
        x, Xbf, (long long)N_NODES * 256);

    // pack weight pairs [Wl|Wr]
    pack2_k<<<(16384 + 255) / 256, 256, 0, stream>>>(W1l, W1r, pB1, 256, 256);
    pack2_k<<<(8192 + 255) / 256, 256, 0, stream>>>(W2l, W2r, pB2, 256, 128);
    pack2_k<<<(2048 + 255) / 256, 256, 0, stream>>>(W3l, W3r, pB3, 128, 64);

    int gemmGrid = MP / 64;                      // 782
    int aggGrid = (N_NODES * 64 + 255) / 256;    // 12500
    float* hout = (float*)d_out;
    float* lout = hout + (long long)N_NODES * 64;

    // layer 1
    gemm_k<256, 512><<<gemmGrid, 256, 0, stream>>>(Xbf, pB1, C1);
    agg_k<256, true, false><<<aggGrid, 256, 0, stream>>>(
        C1, offs, csrc, b1, H1, nullptr, nullptr, N_NODES);
    // layer 2
    gemm_k<256, 256><<<gemmGrid, 256, 0, stream>>>(H1, pB2, C2);
    agg_k<128, true, false><<<aggGrid, 256, 0, stream>>>(
        C2, offs, csrc, b2, H2, nullptr, nullptr, N_NODES);
    // layer 3 (+ fused log_softmax)
    gemm_k<128, 128><<<gemmGrid, 256, 0, stream>>>(H2, pB3, C3);
    agg_k<64, false, true><<<aggGrid, 256, 0, stream>>>(
        C3, offs, csrc, b3, nullptr, hout, lout, N_NODES);
}